// Round 4
// baseline (199.262 us; speedup 1.0000x reference)
//
#include <hip/hip_runtime.h>
#include <hip/hip_bf16.h>

typedef __attribute__((ext_vector_type(8))) short short8;
typedef __attribute__((ext_vector_type(16))) float floatx16;

#define BDIM 512

constexpr int kCIN = 256, kCOUT = 256, kH = 64, kW = 64;
constexpr int BK = 32;                  // ci per chunk
constexpr int NCHUNK = kCIN / BK;       // 8
constexpr int ROWS = 4;                 // output rows per block
constexpr int XR = ROWS + 2, XC = 66, NPIX = XR * XC;  // 396 halo pixels
constexpr int HW = kH * kW;
constexpr int NSTEP = NCHUNK * 9;       // 72

// K-major LDS layouts (all accesses contiguous per 32-lane half => conflict-free):
//   xs: [buf2][g=0..3][pix][16B]   ws: [buf3][g=0..3][co][16B]
constexpr int XS_PLANE = NPIX * 16;
constexpr int XS_BUF   = 4 * XS_PLANE;  // 25.3 KB
constexpr int WS_PLANE = 256 * 16;
constexpr int WS_BUF   = 4 * WS_PLANE;  // 16 KB

__device__ __forceinline__ unsigned short f2bf(float f) {
    unsigned u = __float_as_uint(f);
    u += 0x7fffu + ((u >> 16) & 1u);   // RNE
    return (unsigned short)(u >> 16);
}

// weight[co][ci][kh][kw] fp32 -> wt2[kk][chunk][g][co][j] bf16 (ci=chunk*32+g*8+j)
__global__ void wt_transform_kernel(const float* __restrict__ wsrc,
                                    unsigned short* __restrict__ wt2) {
    int idx = blockIdx.x * 256 + threadIdx.x;
    if (idx >= 9 * 256 * 256) return;
    int j  = idx & 7;
    int co = (idx >> 3) & 255;
    int g  = (idx >> 11) & 3;
    int chunk = (idx >> 13) & 7;
    int kk = idx >> 16;
    int ci = chunk * 32 + g * 8 + j;
    wt2[idx] = f2bf(wsrc[(co * 256 + ci) * 9 + kk]);
}

// Block: 256 cout x 256 pixels (4 rows). 8 waves = 2(co-group) x 4(row).
// Wave tile: 128 co x 64 pix, 4x2 frags of 32x32x16 MFMA.
// Schedule: triple-buffered W DMA, 2-deep prefetch, ONE raw s_barrier per step
// with counted s_waitcnt vmcnt(2) (never drains to 0 in the main loop).
__global__ __launch_bounds__(BDIM, 2)
void conv3x3_mfma_kernel(const float* __restrict__ x,
                         const unsigned short* __restrict__ wt2,
                         const float* __restrict__ bias,
                         float* __restrict__ out) {
    __shared__ __align__(16) char xs[2 * XS_BUF];   // 50.7 KB
    __shared__ __align__(16) char ws[3 * WS_BUF];   // 49.2 KB

    const int bid = blockIdx.x;
    const int b  = bid >> 4;            // 16 h-tiles per image
    const int h0 = (bid & 15) * ROWS;

    const int tid = threadIdx.x;
    const int wv  = tid >> 6;
    const int l   = tid & 63;
    const int l31 = l & 31;
    const int hi2 = l >> 5;
    const int cog  = (wv & 1) * 128;    // wave's cout base
    const int wrow = wv >> 1;           // wave's output row (0..3)

    const float* xb = x + (size_t)b * kCIN * HW;

    floatx16 acc[4][2] = {};            // [co frag][pix frag]

    // W staging via global_load_lds: 16 wave-calls per 16KB tile, 2 per wave.
    // Exactly 2 vmcnt-ops per wave per stageW -> counted waits are exact.
    auto stageW = [&](int st) {
        int chunk = st / 9, kk = st - chunk * 9;
        char* wbuf = ws + (st % 3) * WS_BUF;
        const unsigned short* wp = wt2 + (size_t)(kk * 8 + chunk) * 8192;
        #pragma unroll
        for (int it = 0; it < 2; ++it) {
            int c = wv * 2 + it;
            int g = c >> 2;
            int row0 = (c & 3) * 64;
            const unsigned short* src = wp + (g * 256 + row0 + l) * 8;
            __builtin_amdgcn_global_load_lds(
                (const __attribute__((address_space(1))) unsigned int*)src,
                (__attribute__((address_space(3))) unsigned int*)
                    (wbuf + g * WS_PLANE + row0 * 16),
                16, 0, 0);
        }
    };

    // x halo staging: rows h0-1..h0+ROWS, cols -1..64, 32 ci, fp32->bf16
    auto stageX = [&](int chunk) {
        char* xbuf = xs + (chunk & 1) * XS_BUF;
        const int ci0 = chunk * BK;
        for (int t = tid; t < NPIX * 4; t += BDIM) {
            int g = t / NPIX;
            int rem = t - g * NPIX;
            int r = rem / XC;
            int c = rem - r * XC;
            int ih = h0 - 1 + r;
            int iw = c - 1;
            float v[8];
            if ((unsigned)ih < (unsigned)kH && (unsigned)iw < (unsigned)kW) {
                const float* p = xb + (size_t)(ci0 + g * 8) * HW + ih * kW + iw;
                #pragma unroll
                for (int j = 0; j < 8; ++j) v[j] = p[(size_t)j * HW];
            } else {
                #pragma unroll
                for (int j = 0; j < 8; ++j) v[j] = 0.f;
            }
            union { short8 s8; unsigned short u[8]; } pk;
            #pragma unroll
            for (int j = 0; j < 8; ++j) pk.u[j] = f2bf(v[j]);
            int pix = r * XC + c;
            *(short8*)(xbuf + g * XS_PLANE + pix * 16) = pk.s8;
        }
    };

    stageX(0);
    stageW(0);
    stageW(1);
    __syncthreads();                    // prologue drain (once)

    int chunk = 0, kk = 0;
    #pragma unroll 1
    for (int t = 0; t < NSTEP; ++t) {
        if (t + 2 < NSTEP) stageW(t + 2);   // 2-deep prefetch, buf (t+2)%3

        const char* wbuf = ws + (t % 3) * WS_BUF;
        const char* xbuf = xs + (chunk & 1) * XS_BUF;
        const int kh = kk / 3, kwo = kk - kh * 3;
        const int r = wrow + kh;

        short8 a[2][4], bfr[2][2];
        #pragma unroll
        for (int s = 0; s < 2; ++s) {
            const int g = s * 2 + hi2;
            #pragma unroll
            for (int i = 0; i < 4; ++i) {
                int co = cog + i * 32 + l31;
                a[s][i] = *(const short8*)(wbuf + g * WS_PLANE + co * 16);
            }
            #pragma unroll
            for (int f = 0; f < 2; ++f) {
                int pix = r * XC + f * 32 + l31 + kwo;
                bfr[s][f] = *(const short8*)(xbuf + g * XS_PLANE + pix * 16);
            }
        }
        #pragma unroll
        for (int s = 0; s < 2; ++s)
            #pragma unroll
            for (int i = 0; i < 4; ++i)
                #pragma unroll
                for (int f = 0; f < 2; ++f)
                    acc[i][f] = __builtin_amdgcn_mfma_f32_32x32x16_bf16(
                        a[s][i], bfr[s][f], acc[i][f], 0, 0, 0);

        if (kk == 8 && t < NSTEP - 1) stageX(chunk + 1);  // overlapped restage

        // tile t+1 must be complete before the next step; leave t+2's 2 DMA
        // loads in flight across the barrier (T4: never vmcnt(0) mid-loop).
        __builtin_amdgcn_sched_barrier(0);
        if (t + 2 < NSTEP) {
            asm volatile("s_waitcnt vmcnt(2) lgkmcnt(0)" ::: "memory");
        } else if (t + 1 < NSTEP) {
            asm volatile("s_waitcnt vmcnt(0) lgkmcnt(0)" ::: "memory");
        }
        if (t < NSTEP - 1) {
            __builtin_amdgcn_sched_barrier(0);
            __builtin_amdgcn_s_barrier();
            __builtin_amdgcn_sched_barrier(0);
        }

        kk++;
        if (kk == 9) { kk = 0; chunk++; }
    }

    // epilogue: 32x32 C/D: col=lane&31 (pixel w), row=(reg&3)+8*(reg>>2)+4*(lane>>5) (co)
    float* op = out + (size_t)b * kCOUT * HW + (size_t)(h0 + wrow) * kW;
    #pragma unroll
    for (int i = 0; i < 4; ++i) {
        #pragma unroll
        for (int rg = 0; rg < 16; ++rg) {
            int co = cog + i * 32 + (rg & 3) + 8 * (rg >> 2) + 4 * hi2;
            float bv = bias[co];
            #pragma unroll
            for (int f = 0; f < 2; ++f) {
                op[(size_t)co * HW + f * 32 + l31] = acc[i][f][rg] + bv;
            }
        }
    }
}

extern "C" void kernel_launch(void* const* d_in, const int* in_sizes, int n_in,
                              void* d_out, int out_size, void* d_ws, size_t ws_size,
                              hipStream_t stream) {
    const float* x    = (const float*)d_in[0];
    const float* wsrc = (const float*)d_in[1];
    const float* bias = (const float*)d_in[2];
    float* out = (float*)d_out;
    unsigned short* wt2 = (unsigned short*)d_ws;  // 9*256*256*2 = 1.18 MB scratch

    hipLaunchKernelGGL(wt_transform_kernel, dim3((9 * 256 * 256 + 255) / 256),
                       dim3(256), 0, stream, wsrc, wt2);

    hipLaunchKernelGGL(conv3x3_mfma_kernel, dim3(32 * (kH / ROWS)), dim3(BDIM),
                       0, stream, x, wt2, bias, out);
}

// Round 5
// 158.961 us; speedup vs baseline: 1.2535x; 1.2535x over previous
//
#include <hip/hip_runtime.h>
#include <hip/hip_bf16.h>

typedef __attribute__((ext_vector_type(8))) short short8;
typedef __attribute__((ext_vector_type(16))) float floatx16;

#define BDIM 512

constexpr int kCIN = 256, kCOUT = 256, kH = 64, kW = 64;
constexpr int BK = 32;                  // ci per chunk
constexpr int NCHUNK = kCIN / BK;       // 8
constexpr int ROWS = 4;                 // output rows per block
constexpr int XR = ROWS + 2, XC = 66, NPIX = XR * XC;  // 396 halo pixels
constexpr int HW = kH * kW;
constexpr int GROUPS = NCHUNK * 3;      // 24 (one group = one kh row of taps)

// K-major LDS layouts (contiguous per 32-lane half => conflict-free):
//   xs: [buf2][g=0..3][pix][16B]   ws: [buf2][tap j=0..2][g=0..3][co][16B]
constexpr int XS_PLANE = NPIX * 16;
constexpr int XS_BUF   = 4 * XS_PLANE;   // 25.3 KB
constexpr int WS_PLANE = 256 * 16;
constexpr int WS_TILE  = 4 * WS_PLANE;   // 16 KB
constexpr int WS_GRP   = 3 * WS_TILE;    // 48 KB

__device__ __forceinline__ unsigned short f2bf(float f) {
    unsigned u = __float_as_uint(f);
    u += 0x7fffu + ((u >> 16) & 1u);   // RNE
    return (unsigned short)(u >> 16);
}

// weight[co][ci][kh][kw] fp32 -> wt2[kk][chunk][g][co][j] bf16 (ci=chunk*32+g*8+j)
__global__ void wt_transform_kernel(const float* __restrict__ wsrc,
                                    unsigned short* __restrict__ wt2) {
    int idx = blockIdx.x * 256 + threadIdx.x;
    if (idx >= 9 * 256 * 256) return;
    int j  = idx & 7;
    int co = (idx >> 3) & 255;
    int g  = (idx >> 11) & 3;
    int chunk = (idx >> 13) & 7;
    int kk = idx >> 16;
    int ci = chunk * 32 + g * 8 + j;
    wt2[idx] = f2bf(wsrc[(co * 256 + ci) * 9 + kk]);
}

// Block: 256 cout x 256 pixels (4 rows). 8 waves = 2(co-group) x 4(row).
// Wave tile: 128 co x 64 pix, 4x2 frags of 32x32x16 MFMA.
// Schedule: ONE barrier per 3-tap group (48 MFMA/wave between barriers).
// W triple-tile double-buffered via global_load_lds; end-of-group vmcnt(0)
// is free (loads issued a full group earlier). x restaged 3 groups early.
__global__ __launch_bounds__(BDIM, 2)
void conv3x3_mfma_kernel(const float* __restrict__ x,
                         const unsigned short* __restrict__ wt2,
                         const float* __restrict__ bias,
                         float* __restrict__ out) {
    __shared__ __align__(16) char xs[2 * XS_BUF];   // 50.7 KB
    __shared__ __align__(16) char ws[2 * WS_GRP];   // 96 KB

    const int bid = blockIdx.x;
    const int b  = bid >> 4;            // 16 h-tiles per image
    const int h0 = (bid & 15) * ROWS;

    const int tid = threadIdx.x;
    const int wv  = tid >> 6;
    const int l   = tid & 63;
    const int l31 = l & 31;
    const int hi2 = l >> 5;
    const int cog  = (wv & 1) * 128;    // wave's cout base
    const int wrow = wv >> 1;           // wave's output row (0..3)

    const float* xb = x + (size_t)b * kCIN * HW;

    floatx16 acc[4][2] = {};            // [co frag][pix frag]

    // Stage the 3 W tiles of group grp (chunk=grp/3, kh=grp%3) into buf grp&1.
    // 6 global_load_lds per wave per group; per-lane global src contiguous.
    auto stageW3 = [&](int grp) {
        int chunk = grp / 3, kh = grp % 3;
        char* gbuf = ws + (grp & 1) * WS_GRP;
        #pragma unroll
        for (int j = 0; j < 3; ++j) {
            int kk = kh * 3 + j;
            const unsigned short* wp = wt2 + (size_t)(kk * 8 + chunk) * 8192;
            char* wbuf = gbuf + j * WS_TILE;
            #pragma unroll
            for (int it = 0; it < 2; ++it) {
                int c = wv * 2 + it;
                int g = c >> 2;
                int row0 = (c & 3) * 64;
                const unsigned short* src = wp + (g * 256 + row0 + l) * 8;
                __builtin_amdgcn_global_load_lds(
                    (const __attribute__((address_space(1))) unsigned int*)src,
                    (__attribute__((address_space(3))) unsigned int*)
                        (wbuf + g * WS_PLANE + row0 * 16),
                    16, 0, 0);
            }
        }
    };

    // x halo staging: rows h0-1..h0+ROWS, cols -1..64, 32 ci, fp32->bf16
    auto stageX = [&](int chunk) {
        char* xbuf = xs + (chunk & 1) * XS_BUF;
        const int ci0 = chunk * BK;
        for (int t = tid; t < NPIX * 4; t += BDIM) {
            int g = t / NPIX;
            int rem = t - g * NPIX;
            int r = rem / XC;
            int c = rem - r * XC;
            int ih = h0 - 1 + r;
            int iw = c - 1;
            float v[8];
            if ((unsigned)ih < (unsigned)kH && (unsigned)iw < (unsigned)kW) {
                const float* p = xb + (size_t)(ci0 + g * 8) * HW + ih * kW + iw;
                #pragma unroll
                for (int j = 0; j < 8; ++j) v[j] = p[(size_t)j * HW];
            } else {
                #pragma unroll
                for (int j = 0; j < 8; ++j) v[j] = 0.f;
            }
            union { short8 s8; unsigned short u[8]; } pk;
            #pragma unroll
            for (int j = 0; j < 8; ++j) pk.u[j] = f2bf(v[j]);
            int pix = r * XC + c;
            *(short8*)(xbuf + g * XS_PLANE + pix * 16) = pk.s8;
        }
    };

    stageX(0);
    stageW3(0);
    __syncthreads();                    // prologue drain (once)

    #pragma unroll 1
    for (int grp = 0; grp < GROUPS; ++grp) {
        const int chunk = grp / 3;
        const int kh = grp % 3;

        if (grp + 1 < GROUPS) stageW3(grp + 1);           // fire-and-forget DMA
        if (kh == 0 && chunk + 1 < NCHUNK) stageX(chunk + 1);  // 3 groups early

        const char* gbuf = ws + (grp & 1) * WS_GRP;
        const char* xbuf = xs + (chunk & 1) * XS_BUF;
        const int r = wrow + kh;

        #pragma unroll
        for (int kwo = 0; kwo < 3; ++kwo) {
            const char* wbuf = gbuf + kwo * WS_TILE;
            short8 a[2][4], bfr[2][2];
            #pragma unroll
            for (int s = 0; s < 2; ++s) {
                const int g = s * 2 + hi2;
                #pragma unroll
                for (int i = 0; i < 4; ++i) {
                    int co = cog + i * 32 + l31;
                    a[s][i] = *(const short8*)(wbuf + g * WS_PLANE + co * 16);
                }
                #pragma unroll
                for (int f = 0; f < 2; ++f) {
                    int pix = r * XC + f * 32 + l31 + kwo;
                    bfr[s][f] = *(const short8*)(xbuf + g * XS_PLANE + pix * 16);
                }
            }
            #pragma unroll
            for (int s = 0; s < 2; ++s)
                #pragma unroll
                for (int i = 0; i < 4; ++i)
                    #pragma unroll
                    for (int f = 0; f < 2; ++f)
                        acc[i][f] = __builtin_amdgcn_mfma_f32_32x32x16_bf16(
                            a[s][i], bfr[s][f], acc[i][f], 0, 0, 0);
        }

        // group boundary: next group's W (and any restaged x) must be visible.
        // DMA was issued a full group (~3000 cyc) ago -> drain is ~free.
        if (grp + 1 < GROUPS) {
            __builtin_amdgcn_sched_barrier(0);
            asm volatile("s_waitcnt vmcnt(0) lgkmcnt(0)" ::: "memory");
            __builtin_amdgcn_sched_barrier(0);
            __builtin_amdgcn_s_barrier();
            __builtin_amdgcn_sched_barrier(0);
        }
    }

    // epilogue: 32x32 C/D: col=lane&31 (pixel w), row=(reg&3)+8*(reg>>2)+4*(lane>>5) (co)
    float* op = out + (size_t)b * kCOUT * HW + (size_t)(h0 + wrow) * kW;
    #pragma unroll
    for (int i = 0; i < 4; ++i) {
        #pragma unroll
        for (int rg = 0; rg < 16; ++rg) {
            int co = cog + i * 32 + (rg & 3) + 8 * (rg >> 2) + 4 * hi2;
            float bv = bias[co];
            #pragma unroll
            for (int f = 0; f < 2; ++f) {
                op[(size_t)co * HW + f * 32 + l31] = acc[i][f][rg] + bv;
            }
        }
    }
}

extern "C" void kernel_launch(void* const* d_in, const int* in_sizes, int n_in,
                              void* d_out, int out_size, void* d_ws, size_t ws_size,
                              hipStream_t stream) {
    const float* x    = (const float*)d_in[0];
    const float* wsrc = (const float*)d_in[1];
    const float* bias = (const float*)d_in[2];
    float* out = (float*)d_out;
    unsigned short* wt2 = (unsigned short*)d_ws;  // 9*256*256*2 = 1.18 MB scratch

    hipLaunchKernelGGL(wt_transform_kernel, dim3((9 * 256 * 256 + 255) / 256),
                       dim3(256), 0, stream, wsrc, wt2);

    hipLaunchKernelGGL(conv3x3_mfma_kernel, dim3(32 * (kH / ROWS)), dim3(BDIM),
                       0, stream, x, wt2, bias, out);
}